// Round 1
// baseline (15101.575 us; speedup 1.0000x reference)
//
#include <hip/hip_runtime.h>
#include <hip/hip_fp16.h>

// Neural CDE forward, MI355X. One persistent kernel: 254 RK4 steps x 4 vector-field
// evals, all in registers/LDS. f16 MFMA (16x16x32) for the 3 MLP matmuls + readout,
// fp32 everywhere else. Transposed orientation (batch = N = lane&15, invariant across
// the chain); hidden-feature spaces permuted at weight-prepack time so each stage's
// C-output repacks into the next stage's B-fragment with per-lane ops only.
//
// Wave = 16 batch cols. 256 blocks x 256 thr (4 waves) = 1024 waves = 1/SIMD.
// LDS: 106 A-frags (f16, frag-order, lane-linear reads) + biases = 110720 B.

typedef _Float16 f16;
typedef _Float16 f16x8 __attribute__((ext_vector_type(8)));
typedef float f32x4 __attribute__((ext_vector_type(4)));

#define NFRAG 106
#define LDS_BYTES (NFRAG*1024 + 512 + 512 + 1024 + 128)

__device__ __forceinline__ float tanhf_fast(float x) {
    float e = __expf(x + x);                       // v_exp_f32 path
    return fmaf(-2.0f, __builtin_amdgcn_rcpf(e + 1.0f), 1.0f);
    // x->+inf: e=inf -> 1 ; x->-inf: e=0 -> -1 ; err ~1e-7
}

__global__ __launch_bounds__(256, 1) void ncde_kernel(
    const float* __restrict__ coeffs,
    const float* __restrict__ iW1, const float* __restrict__ ib1,
    const float* __restrict__ iW2, const float* __restrict__ ib2,
    const float* __restrict__ fW1, const float* __restrict__ fb1,
    const float* __restrict__ fW2, const float* __restrict__ fb2,
    const float* __restrict__ fW3, const float* __restrict__ fb3,
    const float* __restrict__ rW1, const float* __restrict__ rb1,
    const float* __restrict__ rW2, const float* __restrict__ rb2,
    float* __restrict__ out)
{
    extern __shared__ char smem[];
    f16*   wf    = (f16*)smem;                 // 106 frags * 64 lanes * 8 f16
    float* bias1 = (float*)(smem + NFRAG*1024);
    float* bias2 = bias1 + 128;
    float* bias3 = bias2 + 128;
    float* rb1s  = bias3 + 256;

    const int tid = threadIdx.x;

    // ---------------- weight pre-pack (once; identical every launch) -------------
    // A-frag (16x16x32): lane lv: out-row = mo*16 + (lv&15), k-slot = 8*(lv>>4)+j.
    // K-slot -> original-feature mappings (the "zero-shuffle" permutations):
    //   z-space   (mm1/readout K): h  = 2*(8*(q&1)+j) + (q>>1)
    //   hid-space (mm2/mm3 K):     f1 = 16*((8*kb+j)>>2) + 4*q + ((8*kb+j)&3)
    for (int slot = tid; slot < NFRAG*64; slot += 256) {
        const int frag = slot >> 6, lv = slot & 63;
        const int qv = lv >> 4, mrow = lv & 15;
        f16x8 v;
        if (frag < 8) {                         // mm1: A = W1^T, frags [mo 0..7]
            const int mo = frag;
            #pragma unroll
            for (int j = 0; j < 8; ++j) {
                int h = 2*(8*(qv&1) + j) + (qv>>1);
                v[j] = (f16)fW1[h*128 + mo*16 + mrow];
            }
        } else if (frag < 40) {                 // mm2: [8 + mo*4 + kb]
            const int mo = (frag-8) >> 2, kb = (frag-8) & 3;
            #pragma unroll
            for (int j = 0; j < 8; ++j) {
                int n = kb*8 + j;
                int f1 = 16*(n>>2) + 4*qv + (n&3);
                v[j] = (f16)fW2[f1*128 + mo*16 + mrow];
            }
        } else if (frag < 104) {                // mm3: [40 + mo*4 + kb], mo 0..15
            const int mo = (frag-40) >> 2, kb = (frag-40) & 3;
            #pragma unroll
            for (int j = 0; j < 8; ++j) {
                int n = kb*8 + j;
                int f1 = 16*(n>>2) + 4*qv + (n&3);
                v[j] = (f16)fW3[f1*256 + mo*16 + mrow];
            }
        } else {                                // readout: rW1^T, frags [104,105]
            const int mo = frag - 104;
            #pragma unroll
            for (int j = 0; j < 8; ++j) {
                int h = 2*(8*(qv&1) + j) + (qv>>1);
                v[j] = (f16)rW1[h*32 + mo*16 + mrow];
            }
        }
        *(f16x8*)(wf + (size_t)slot*8) = v;
    }
    for (int i = tid; i < 128; i += 256) { bias1[i] = fb1[i]; bias2[i] = fb2[i]; }
    if (tid < 256) bias3[tid] = fb3[tid];
    if (tid < 32)  rb1s[tid]  = rb1[tid];
    __syncthreads();

    // ---------------- per-lane identities ----------------------------------------
    const int l   = tid & 63;
    const int q   = l >> 4;          // quarter-wave
    const int col = l & 15;          // batch column within wave tile
    const int q4  = 4*q;
    const int pp  = q >> 1;          // h-parity this lane owns (z[2i+pp])
    const int qlo = (q & 1) * 8;     // base into u[] for the mm1 B-frag
    const int ch  = (q & 1) * 4;     // spline-channel base (c = ch + r)
    const int b   = blockIdx.x*64 + (tid >> 6)*16 + col;
    const float* cb_ptr = coeffs + (size_t)b * (127*32);  // [piece][a8,b8,2c8,3d8]

    float rw2r[8];
    #pragma unroll
    for (int mo = 0; mo < 2; ++mo)
        #pragma unroll
        for (int r = 0; r < 4; ++r) rw2r[mo*4+r] = rW2[mo*16 + q4 + r];
    const float rb2v = rb2[0];

    // ---------------- z0 = relu(X0@iW1+ib1)@iW2+ib2  (X0 = a[:,0]) ---------------
    float z[16];
    {
        f32x4 a0 = *(const f32x4*)(cb_ptr);
        f32x4 a1 = *(const f32x4*)(cb_ptr + 4);
        float X0[8];
        #pragma unroll
        for (int i = 0; i < 4; ++i) { X0[i] = a0[i]; X0[4+i] = a1[i]; }
        float hid[64];
        #pragma unroll
        for (int m = 0; m < 64; ++m) {
            float hv = ib1[m];
            #pragma unroll
            for (int i = 0; i < 8; ++i) hv = fmaf(X0[i], iW1[i*64 + m], hv);
            hid[m] = fmaxf(hv, 0.0f);
        }
        #pragma unroll
        for (int i = 0; i < 16; ++i) {
            int h = 2*i + pp;
            float zz = ib2[h];
            #pragma unroll
            for (int m = 0; m < 64; ++m) zz = fmaf(hid[m], iW2[m*32 + h], zz);
            z[i] = zz;
        }
    }

    // ---------------- readout: y = relu(z@rW1+rb1)@rW2+rb2 (2 MFMAs) -------------
    auto do_readout = [&](int knot) {
        f16x8 bz;
        #pragma unroll
        for (int jj = 0; jj < 8; ++jj) bz[jj] = (f16)z[qlo + jj];
        float y = 0.0f;
        #pragma unroll
        for (int mo = 0; mo < 2; ++mo) {
            f32x4 acc = *(const f32x4*)(rb1s + mo*16 + q4);
            f16x8 a = *(const f16x8*)(wf + (size_t)((104+mo)*64 + l)*8);
            acc = __builtin_amdgcn_mfma_f32_16x16x32_f16(a, bz, acc, 0, 0, 0);
            #pragma unroll
            for (int r = 0; r < 4; ++r) y = fmaf(fmaxf(acc[r], 0.0f), rw2r[mo*4+r], y);
        }
        y += __shfl_xor(y, 16);      // merge j-quarters
        y += __shfl_xor(y, 32);
        y += rb2v;
        if (q == 0) out[(size_t)b*128 + knot] = y;
    };

    // ---------------- one vector-field eval g(t,u): k = tanh(MLP(u)) . dX --------
    auto geval = [&](const float (&u)[16], const float (&dxc)[4], float (&kout)[16]) {
        f16x8 bz;
        #pragma unroll
        for (int jj = 0; jj < 8; ++jj) bz[jj] = (f16)u[qlo + jj];
        // mm1: 128 <- 32
        float c1[32];
        #pragma unroll
        for (int mo = 0; mo < 8; ++mo) {
            f32x4 acc = *(const f32x4*)(bias1 + mo*16 + q4);
            f16x8 a = *(const f16x8*)(wf + (size_t)(mo*64 + l)*8);
            acc = __builtin_amdgcn_mfma_f32_16x16x32_f16(a, bz, acc, 0, 0, 0);
            #pragma unroll
            for (int r = 0; r < 4; ++r) c1[mo*4+r] = tanhf_fast(acc[r]);
        }
        f16x8 b2[4];                 // identity repack by construction
        #pragma unroll
        for (int kb = 0; kb < 4; ++kb)
            #pragma unroll
            for (int jj = 0; jj < 8; ++jj) b2[kb][jj] = (f16)c1[kb*8 + jj];
        // mm2: 128 <- 128
        float c2[32];
        #pragma unroll
        for (int mo = 0; mo < 8; ++mo) {
            f32x4 acc = *(const f32x4*)(bias2 + mo*16 + q4);
            #pragma unroll
            for (int kb = 0; kb < 4; ++kb) {
                f16x8 a = *(const f16x8*)(wf + (size_t)((8 + mo*4 + kb)*64 + l)*8);
                acc = __builtin_amdgcn_mfma_f32_16x16x32_f16(a, b2[kb], acc, 0, 0, 0);
            }
            #pragma unroll
            for (int r = 0; r < 4; ++r) c2[mo*4+r] = tanhf_fast(acc[r]);
        }
        f16x8 b3[4];
        #pragma unroll
        for (int kb = 0; kb < 4; ++kb)
            #pragma unroll
            for (int jj = 0; jj < 8; ++jj) b3[kb][jj] = (f16)c2[kb*8 + jj];
        // mm3: 256 <- 128, einsum fused per tile. lane covers (h = 2*mo + pp, c = ch+r)
        #pragma unroll
        for (int mo = 0; mo < 16; ++mo) {
            f32x4 acc = *(const f32x4*)(bias3 + mo*16 + q4);
            #pragma unroll
            for (int kb = 0; kb < 4; ++kb) {
                f16x8 a = *(const f16x8*)(wf + (size_t)((40 + mo*4 + kb)*64 + l)*8);
                acc = __builtin_amdgcn_mfma_f32_16x16x32_f16(a, b3[kb], acc, 0, 0, 0);
            }
            float s = 0.0f;
            #pragma unroll
            for (int r = 0; r < 4; ++r) s = fmaf(tanhf_fast(acc[r]), dxc[r], s);
            kout[mo] = s;
        }
        #pragma unroll
        for (int i = 0; i < 16; ++i) kout[i] += __shfl_xor(kout[i], 16); // c-half merge
    };

    // ---------------- time loop: 254 RK4 (3/8 rule) steps ------------------------
    const float C_DT3 = 0.5f / 3.0f;
    float cbr[4], ctr[4], cdr[4];
    do_readout(0);

    #pragma unroll 1
    for (int s = 0; s < 254; ++s) {
        const int p = s >> 1;
        if ((s & 1) == 0) {          // new spline piece: load b_, 2c, 3d (this lane's 4 ch)
            const float* cp = cb_ptr + (size_t)p*32 + ch;
            f32x4 vb = *(const f32x4*)(cp + 8);
            f32x4 vc = *(const f32x4*)(cp + 16);
            f32x4 vd = *(const f32x4*)(cp + 24);
            #pragma unroll
            for (int r = 0; r < 4; ++r) { cbr[r] = vb[r]; ctr[r] = vc[r]; cdr[r] = vd[r]; }
        }
        // t/frac computed with the reference's exact fp32 op order
        const float t0 = 0.5f * (float)s;
        const float pf = (float)p;
        const float fr1 = t0 - pf;
        const float fr2 = (t0 + 0.5f/3.0f) - pf;
        const float fr3 = (t0 + 1.0f/3.0f) - pf;
        float dxc1[4], dxc2[4], dxc3[4], dxc4[4];
        #pragma unroll
        for (int r = 0; r < 4; ++r) {
            dxc1[r] = fmaf(fmaf(cdr[r], fr1, ctr[r]), fr1, cbr[r]);
            dxc2[r] = fmaf(fmaf(cdr[r], fr2, ctr[r]), fr2, cbr[r]);
            dxc3[r] = fmaf(fmaf(cdr[r], fr3, ctr[r]), fr3, cbr[r]);
        }
        if ((s & 1) == 0) {          // t4 = p + 0.5, same piece
            #pragma unroll
            for (int r = 0; r < 4; ++r) dxc4[r] = fmaf(fmaf(cdr[r], 0.5f, ctr[r]), 0.5f, cbr[r]);
        } else if (p < 126) {        // t4 integer -> next piece, frac 0 -> dX = b_
            f32x4 vb2 = *(const f32x4*)(cb_ptr + (size_t)(p+1)*32 + ch + 8);
            #pragma unroll
            for (int r = 0; r < 4; ++r) dxc4[r] = vb2[r];
        } else {                     // s = 253: idx clips to 126, frac = 1
            #pragma unroll
            for (int r = 0; r < 4; ++r) dxc4[r] = cbr[r] + (ctr[r] + cdr[r]);
        }

        float k1[16], k2[16], k3[16], k4[16], u[16];
        geval(z, dxc1, k1);
        #pragma unroll
        for (int i = 0; i < 16; ++i) u[i] = fmaf(k1[i], C_DT3, z[i]);
        geval(u, dxc2, k2);
        #pragma unroll
        for (int i = 0; i < 16; ++i) u[i] = fmaf(k2[i], 0.5f, fmaf(k1[i], -C_DT3, z[i]));
        geval(u, dxc3, k3);
        #pragma unroll
        for (int i = 0; i < 16; ++i) u[i] = fmaf(k1[i] - k2[i] + k3[i], 0.5f, z[i]);
        geval(u, dxc4, k4);
        #pragma unroll
        for (int i = 0; i < 16; ++i)
            z[i] = fmaf(k1[i] + 3.0f*(k2[i] + k3[i]) + k4[i], 0.0625f, z[i]);

        if (s & 1) do_readout((s >> 1) + 1);
    }
}

extern "C" void kernel_launch(void* const* d_in, const int* in_sizes, int n_in,
                              void* d_out, int out_size, void* d_ws, size_t ws_size,
                              hipStream_t stream) {
    const float* coeffs = (const float*)d_in[0];
    // d_in[1] = t_eval (arange, unused)
    const float* iW1 = (const float*)d_in[2];
    const float* ib1 = (const float*)d_in[3];
    const float* iW2 = (const float*)d_in[4];
    const float* ib2 = (const float*)d_in[5];
    const float* fW1 = (const float*)d_in[6];
    const float* fb1 = (const float*)d_in[7];
    const float* fW2 = (const float*)d_in[8];
    const float* fb2 = (const float*)d_in[9];
    const float* fW3 = (const float*)d_in[10];
    const float* fb3 = (const float*)d_in[11];
    const float* rW1 = (const float*)d_in[12];
    const float* rb1 = (const float*)d_in[13];
    const float* rW2 = (const float*)d_in[14];
    const float* rb2 = (const float*)d_in[15];
    float* outp = (float*)d_out;

    hipFuncSetAttribute((const void*)ncde_kernel,
                        hipFuncAttributeMaxDynamicSharedMemorySize, LDS_BYTES);
    ncde_kernel<<<dim3(256), dim3(256), LDS_BYTES, stream>>>(
        coeffs, iW1, ib1, iW2, ib2, fW1, fb1, fW2, fb2, fW3, fb3,
        rW1, rb1, rW2, rb2, outp);
}